// Round 1
// baseline (263.263 us; speedup 1.0000x reference)
//
#include <hip/hip_runtime.h>
#include <cmath>

#define WIN 11
#define HALO 5
#define IMG 512
#define TW 64
#define TH 16
#define RH (TH + 2*HALO)   /* 26 rows incl. vertical halo */
#define CW (TW + 2*HALO)   /* 74 cols incl. horizontal halo */
#define S1 76              /* sx/sy row stride (16B-aligned) */
#define S2 TW              /* h-blur buffer row stride */
#define NIMG 48            /* 16 batch * 3 channels */
#define NPIX (16.0 * 3.0 * 512.0 * 512.0)

struct GaussW { float w[WIN]; };

__global__ void __launch_bounds__(64) zero_kernel(float* out) {
    if (threadIdx.x == 0) out[0] = 0.f;
}

__global__ void __launch_bounds__(256) ssim_tile_kernel(
        const float* __restrict__ xin, const float* __restrict__ yin,
        float* __restrict__ out_acc, GaussW W) {
    __shared__ float sx[RH * S1];
    __shared__ float sy[RH * S1];
    __shared__ float hx [RH * S2];
    __shared__ float hy [RH * S2];
    __shared__ float hxx[RH * S2];
    __shared__ float hyy[RH * S2];
    __shared__ float hxy[RH * S2];
    __shared__ float wsum[4];

    const int tid = threadIdx.x;
    const int x0 = blockIdx.x * TW - HALO;
    const int y0 = blockIdx.y * TH - HALO;
    const size_t ibase = (size_t)blockIdx.z * (IMG * IMG);

    // ---- Stage 1: global -> LDS staging (zero outside image = conv zero-pad)
    for (int i = tid; i < RH * CW; i += 256) {
        int r = i / CW;
        int c = i - r * CW;
        int gy = y0 + r, gx = x0 + c;
        float vx = 0.f, vy = 0.f;
        if ((unsigned)gy < IMG && (unsigned)gx < IMG) {
            size_t idx = ibase + (size_t)gy * IMG + (size_t)gx;
            vx = xin[idx];
            vy = yin[idx];
        }
        sx[r * S1 + c] = vx;
        sy[r * S1 + c] = vy;
    }
    __syncthreads();

    // ---- Stage 2: horizontal blur of 5 fields (x, y, x^2, y^2, xy)
    // 4 consecutive outputs per group; float4 LDS reads; products in registers.
    for (int g = tid; g < RH * (TW / 4); g += 256) {
        int r  = g >> 4;
        int c0 = (g & (TW / 4 - 1)) << 2;
        float xv[16], yv[16];
        const float4* pa = (const float4*)&sx[r * S1 + c0];
        const float4* pb = (const float4*)&sy[r * S1 + c0];
        #pragma unroll
        for (int q = 0; q < 4; ++q) {
            float4 a = pa[q], b = pb[q];
            xv[4*q+0] = a.x; xv[4*q+1] = a.y; xv[4*q+2] = a.z; xv[4*q+3] = a.w;
            yv[4*q+0] = b.x; yv[4*q+1] = b.y; yv[4*q+2] = b.z; yv[4*q+3] = b.w;
        }
        float ax[4]  = {0,0,0,0}, ay[4]  = {0,0,0,0};
        float axx[4] = {0,0,0,0}, ayy[4] = {0,0,0,0}, axy[4] = {0,0,0,0};
        #pragma unroll
        for (int k = 0; k < WIN; ++k) {
            float wk = W.w[k];
            #pragma unroll
            for (int o = 0; o < 4; ++o) {
                float xs = xv[o + k], ys = yv[o + k];
                float tx = wk * xs, ty = wk * ys;
                ax[o]  += tx;
                ay[o]  += ty;
                axx[o] += tx * xs;
                ayy[o] += ty * ys;
                axy[o] += tx * ys;
            }
        }
        int ob = r * S2 + c0;
        *(float4*)&hx [ob] = make_float4(ax[0],  ax[1],  ax[2],  ax[3]);
        *(float4*)&hy [ob] = make_float4(ay[0],  ay[1],  ay[2],  ay[3]);
        *(float4*)&hxx[ob] = make_float4(axx[0], axx[1], axx[2], axx[3]);
        *(float4*)&hyy[ob] = make_float4(ayy[0], ayy[1], ayy[2], ayy[3]);
        *(float4*)&hxy[ob] = make_float4(axy[0], axy[1], axy[2], axy[3]);
    }
    __syncthreads();

    // ---- Stage 3: vertical blur (4 rows/thread, shared 14-row window) + SSIM
    const int c  = tid & (TW - 1);
    const int r0 = (tid >> 6) << 2;   // 0,4,8,12

    float mx[4]  = {0,0,0,0}, my[4]  = {0,0,0,0};
    float vxx[4] = {0,0,0,0}, vyy[4] = {0,0,0,0}, vxy[4] = {0,0,0,0};

    auto vblur4 = [&](const float* buf, float acc[4]) {
        float v[14];
        #pragma unroll
        for (int k = 0; k < 14; ++k) v[k] = buf[(r0 + k) * S2 + c];
        #pragma unroll
        for (int k = 0; k < WIN; ++k) {
            float wk = W.w[k];
            #pragma unroll
            for (int o = 0; o < 4; ++o) acc[o] += wk * v[k + o];
        }
    };
    vblur4(hx,  mx);
    vblur4(hy,  my);
    vblur4(hxx, vxx);
    vblur4(hyy, vyy);
    vblur4(hxy, vxy);

    const float C1 = 0.01f * 0.01f;
    const float C2 = 0.03f * 0.03f;
    float local = 0.f;
    #pragma unroll
    for (int o = 0; o < 4; ++o) {
        float mux = mx[o], muy = my[o];
        float mux2 = mux * mux, muy2 = muy * muy, muxy = mux * muy;
        float sxx_ = vxx[o] - mux2;
        float syy_ = vyy[o] - muy2;
        float sxy_ = vxy[o] - muxy;
        float num = (2.f * muxy + C1) * (2.f * sxy_ + C2);
        float den = (mux2 + muy2 + C1) * (sxx_ + syy_ + C2);
        local += num / (den + 1e-8f);
    }

    // ---- block reduce: wave shuffle, then one atomic per block
    #pragma unroll
    for (int off = 32; off > 0; off >>= 1)
        local += __shfl_down(local, off, 64);
    if ((tid & 63) == 0) wsum[tid >> 6] = local;
    __syncthreads();
    if (tid == 0)
        atomicAdd(out_acc, wsum[0] + wsum[1] + wsum[2] + wsum[3]);
}

__global__ void __launch_bounds__(64) finish_kernel(float* out) {
    if (threadIdx.x == 0)
        out[0] = 1.0f - out[0] * (float)(1.0 / NPIX);
}

extern "C" void kernel_launch(void* const* d_in, const int* in_sizes, int n_in,
                              void* d_out, int out_size, void* d_ws, size_t ws_size,
                              hipStream_t stream) {
    const float* x = (const float*)d_in[0];
    const float* y = (const float*)d_in[1];
    float* out = (float*)d_out;

    // Gaussian weights (host, double precision — matches JAX f32 within 1 ulp)
    GaussW gw;
    double g[WIN], s = 0.0;
    for (int i = 0; i < WIN; ++i) {
        double d = (double)(i - WIN / 2);
        g[i] = exp(-(d * d) / (2.0 * 1.5 * 1.5));
        s += g[i];
    }
    for (int i = 0; i < WIN; ++i) gw.w[i] = (float)(g[i] / s);

    hipLaunchKernelGGL(zero_kernel, dim3(1), dim3(64), 0, stream, out);
    dim3 grid(IMG / TW, IMG / TH, NIMG);
    hipLaunchKernelGGL(ssim_tile_kernel, grid, dim3(256), 0, stream, x, y, out, gw);
    hipLaunchKernelGGL(finish_kernel, dim3(1), dim3(64), 0, stream, out);
}